// Round 7
// baseline (228.570 us; speedup 1.0000x reference)
//
#include <hip/hip_runtime.h>
#include <math.h>

#define DIM_    128
#define QH_     16
#define KVH_    4
#define WIN_    512
#define BATCH_  4
#define SEQ_    2048
#define QKV_LD  3072
#define ATT_LD  2048

#define NX   (BATCH_*SEQ_*DIM_)   // 1048576
#define NWQ  (DIM_*QKV_LD)        // 393216
#define NWP  (ATT_LD*DIM_)        // 262144

typedef __attribute__((ext_vector_type(8))) short short8;
typedef __attribute__((ext_vector_type(4))) float f32x4;
typedef unsigned short u16;
typedef unsigned int u32;

__device__ __forceinline__ u16 f2bf(float f) {
    u32 u = __float_as_uint(f);
    u += 0x7fff + ((u >> 16) & 1);
    return (u16)(u >> 16);
}
__device__ __forceinline__ float bf2f(u16 u) {
    return __uint_as_float(((u32)u) << 16);
}
#define MFMA16 __builtin_amdgcn_mfma_f32_16x16x32_bf16

__device__ __forceinline__ void gload_lds16(const u16* g, u16* l) {
    __builtin_amdgcn_global_load_lds(
        (const __attribute__((address_space(1))) unsigned int*)(const void*)g,
        (__attribute__((address_space(3))) unsigned int*)(void*)l, 16, 0, 0);
}

// ---------- convert: xh = bf16(x); wth = bf16(Wqkv^T)[3072][128];
//            wpth = bf16(Wproj^T)[128][2048]
__global__ __launch_bounds__(256) void convert_inputs(
    const float* __restrict__ x, const float* __restrict__ Wqkv,
    const float* __restrict__ Wproj,
    u16* __restrict__ xh, u16* __restrict__ wth, u16* __restrict__ wpth)
{
    const int t = blockIdx.x * 256 + threadIdx.x;
    if (t < NX) {
        xh[t] = f2bf(x[t]);
    } else if (t < NX + NWQ) {
        const int u2 = t - NX;
        const int k = u2 & 127, n = u2 >> 7;
        wth[u2] = f2bf(Wqkv[(size_t)k * QKV_LD + n]);
    } else {
        const int u2 = t - NX - NWQ;
        const int k = u2 & 2047, n = u2 >> 11;
        wpth[u2] = f2bf(Wproj[(size_t)k * DIM_ + n]);
    }
}

// ---------- GEMM1 (bf16 MFMA, LDS-tiled): qkv = x @ Wqkv (unchanged R6) ----
__global__ __launch_bounds__(256) void gemm1_mfma(
    const u16* __restrict__ xh, const u16* __restrict__ wth,
    u16* __restrict__ qkvb, u16* __restrict__ vg)
{
    __shared__ u16 Ab[32][512];
    __shared__ u16 Bb[16][512];
    const int bn = blockIdx.x * 64;
    const int bm = blockIdx.y * 128;
    const int tid = threadIdx.x;
    const int wv = tid >> 6, lane = tid & 63;
    const int lr = lane & 15, quad = lane >> 4;
    const int lo = lane & 15, hi = lane >> 4;

    #pragma unroll
    for (int i = 0; i < 12; ++i) {
        const int idx = wv * 12 + i;
        if (idx < 32) {
            const int mt = idx >> 2, s = idx & 3;
            gload_lds16(xh + (size_t)(bm + mt * 16 + lo) * DIM_ + s * 32 + hi * 8,
                        &Ab[idx][0]);
        } else {
            const int j = idx - 32, nt = j >> 2, s = j & 3;
            gload_lds16(wth + (size_t)(bn + nt * 16 + lo) * DIM_ + s * 32 + hi * 8,
                        &Bb[j][0]);
        }
    }
    __syncthreads();

    const int wr = wv >> 1, wc = wv & 1;
    f32x4 acc[4][2] = {};
    if (bn < 2560) {                       // transposed: ushort4 stores
        #pragma unroll
        for (int s = 0; s < 4; ++s) {
            short8 af[4], bf[2];
            #pragma unroll
            for (int mt = 0; mt < 4; ++mt)
                af[mt] = *(const short8*)&Ab[(wr * 4 + mt) * 4 + s][lane * 8];
            #pragma unroll
            for (int nt = 0; nt < 2; ++nt)
                bf[nt] = *(const short8*)&Bb[(wc * 2 + nt) * 4 + s][lane * 8];
            #pragma unroll
            for (int mt = 0; mt < 4; ++mt)
                #pragma unroll
                for (int nt = 0; nt < 2; ++nt)
                    acc[mt][nt] = MFMA16(bf[nt], af[mt], acc[mt][nt], 0, 0, 0);
        }
        #pragma unroll
        for (int mt = 0; mt < 4; ++mt)
            #pragma unroll
            for (int nt = 0; nt < 2; ++nt) {
                ushort4 o;
                o.x = f2bf(acc[mt][nt][0]); o.y = f2bf(acc[mt][nt][1]);
                o.z = f2bf(acc[mt][nt][2]); o.w = f2bf(acc[mt][nt][3]);
                *(ushort4*)(qkvb
                    + (size_t)(bm + wr * 64 + mt * 16 + lr) * QKV_LD
                    + bn + wc * 32 + nt * 16 + quad * 4) = o;
            }
    } else {                               // V region: normal, seq in regs
        #pragma unroll
        for (int s = 0; s < 4; ++s) {
            short8 af[4], bf[2];
            #pragma unroll
            for (int mt = 0; mt < 4; ++mt)
                af[mt] = *(const short8*)&Ab[(wr * 4 + mt) * 4 + s][lane * 8];
            #pragma unroll
            for (int nt = 0; nt < 2; ++nt)
                bf[nt] = *(const short8*)&Bb[(wc * 2 + nt) * 4 + s][lane * 8];
            #pragma unroll
            for (int mt = 0; mt < 4; ++mt)
                #pragma unroll
                for (int nt = 0; nt < 2; ++nt)
                    acc[mt][nt] = MFMA16(af[mt], bf[nt], acc[mt][nt], 0, 0, 0);
        }
        #pragma unroll
        for (int mt = 0; mt < 4; ++mt)
            #pragma unroll
            for (int nt = 0; nt < 2; ++nt) {
                const int ncol = bn + wc * 32 + nt * 16 + lr - 2560;
                const int kvh = ncol >> 7, d = ncol & 127;
                const int m0 = bm + wr * 64 + mt * 16 + quad * 4;
                ushort4 o;
                o.x = f2bf(acc[mt][nt][0]); o.y = f2bf(acc[mt][nt][1]);
                o.z = f2bf(acc[mt][nt][2]); o.w = f2bf(acc[mt][nt][3]);
                *(ushort4*)(vg + ((size_t)((m0 >> 11) * KVH_ + kvh) * DIM_ + d)
                            * SEQ_ + (m0 & 2047)) = o;
            }
    }
}

// ---------- Attention: block = (b, kvh, 32-q tile), 256 thr, wave = head ---
// Deferred-PV pipeline: per iter [barrier; prefetch ch+1; PV(ch-1); QK(ch)].
// PV(ch-1) and QK(ch) are independent chains -> ILP; no intra-iter LDS wait.
// QK computed transposed (C^T): keys in regs -> ushort4 P stores, query=lane
// -> 2-step quad sum reduction, inv at the lane the O^T epilogue needs.
__global__ __launch_bounds__(256) void attn_mfma(
    const u16* __restrict__ qkvb, const u16* __restrict__ vg,
    u16* __restrict__ ah)
{
    const int qt = blockIdx.x, kvh = blockIdx.y, b = blockIdx.z;
    const int q0 = qt << 5;
    const int tid = threadIdx.x;
    const int wv = tid >> 6, lane = tid & 63;
    const int lr = lane & 15, quad = lane >> 4;
    const int h = kvh * 4 + wv;

    __shared__ u16 Kb[2][8][512];    // 16KB  sub p = nt*4+s
    __shared__ u16 Vb[3][8][512];    // 24KB  sub nt = 16-dim tile
    __shared__ u16 Pt[4][32][36];    // 9KB   per-wave P^T [query][key], +4 pad

    const float scale2 = 0.08838834764831845f * 1.4426950408889634f;
    const float slope2 = exp2f(-0.5f * (float)(h + 1)) * 1.4426950408889634f;
    const int jbase = max(0, q0 - WIN_);
    const int nch = (q0 + 32 - jbase) >> 5;      // 32-key chunks
    const size_t rowb = (size_t)b * SEQ_;
    const u16* kg  = qkvb + rowb * QKV_LD + (QH_ + kvh) * DIM_;
    const u16* vgb = vg + (size_t)(b * KVH_ + kvh) * DIM_ * SEQ_;

    // Q B-frags (query = lane role): qf[qt2][s]
    short8 qf[2][4];
    #pragma unroll
    for (int m = 0; m < 2; ++m) {
        const u16* qp = qkvb + (rowb + q0 + m * 16 + lr) * QKV_LD
                        + h * DIM_ + quad * 8;
        #pragma unroll
        for (int s = 0; s < 4; ++s) qf[m][s] = *(const short8*)(qp + 32 * s);
    }

    f32x4 O[2][8] = {};              // O^T: regs = d, lane col = query
    float rs[2] = {0.f, 0.f};        // per-thread row sums (query = lr)
    const int lo = lane & 15, hi = lane >> 4;

    // stage chunk 0: each wave 2 K-subs + 2 V-subs
    #pragma unroll
    for (int t = 0; t < 2; ++t) {
        const int p = wv + t * 4;
        gload_lds16(kg + (size_t)(jbase + (p >> 2) * 16 + lo) * QKV_LD
                    + (p & 3) * 32 + hi * 8, &Kb[0][p][0]);
        gload_lds16(vgb + (size_t)(p * 16 + lo) * SEQ_ + jbase + hi * 8,
                    &Vb[0][p][0]);
    }

    for (int ch = 0; ch < nch; ++ch) {
        const int jk = jbase + (ch << 5);
        __syncthreads();                          // chunk ch staged
        if (ch + 1 < nch) {                       // prefetch ch+1
            const int jn = jk + 32;
            const int kn = (ch + 1) & 1, vn = (ch + 1) % 3;
            #pragma unroll
            for (int t = 0; t < 2; ++t) {
                const int p = wv + t * 4;
                gload_lds16(kg + (size_t)(jn + (p >> 2) * 16 + lo) * QKV_LD
                            + (p & 3) * 32 + hi * 8, &Kb[kn][p][0]);
                gload_lds16(vgb + (size_t)(p * 16 + lo) * SEQ_ + jn + hi * 8,
                            &Vb[vn][p][0]);
            }
        }

        // ---- PV(ch-1): reads Pt (written last iter, in-order DS) + Vb[(ch-1)%3]
        if (ch > 0) {
            const int vp = (ch - 1) % 3;
            short8 pa0 = *(const short8*)&Pt[wv][lr][quad * 8];
            short8 pa1 = *(const short8*)&Pt[wv][16 + lr][quad * 8];
            #pragma unroll
            for (int nt = 0; nt < 8; ++nt) {
                short8 vf = *(const short8*)&Vb[vp][nt][lane * 8];
                O[0][nt] = MFMA16(vf, pa0, O[0][nt], 0, 0, 0);
                O[1][nt] = MFMA16(vf, pa1, O[1][nt], 0, 0, 0);
            }
        }

        // ---- QK(ch) transposed: c = MFMA(kf, qf) -> C^T[key][query]
        const int kb = ch & 1;
        #pragma unroll
        for (int nt = 0; nt < 2; ++nt) {
            f32x4 c0 = {0.f, 0.f, 0.f, 0.f}, c1 = {0.f, 0.f, 0.f, 0.f};
            #pragma unroll
            for (int s = 0; s < 4; ++s) {
                short8 kf = *(const short8*)&Kb[kb][nt * 4 + s][lane * 8];
                c0 = MFMA16(kf, qf[0][s], c0, 0, 0, 0);
                c1 = MFMA16(kf, qf[1][s], c1, 0, 0, 0);
            }
            const int j0 = jk + nt * 16 + quad * 4;
            #pragma unroll
            for (int m = 0; m < 2; ++m) {
                const f32x4 c = m ? c1 : c0;
                const int q = q0 + m * 16 + lr;
                const int relmax = (q < WIN_) ? q : WIN_;
                ushort4 o;
                u16* op = (u16*)&o;
                #pragma unroll
                for (int r = 0; r < 4; ++r) {
                    const int rel = q - (j0 + r);
                    float e = 0.f;
                    if (rel >= 0 && rel <= WIN_)
                        e = exp2f(fmaf(c[r], scale2,
                                       slope2 * (float)(rel - relmax)));
                    rs[m] += e;
                    op[r] = f2bf(e);
                }
                *(ushort4*)&Pt[wv][m * 16 + lr][nt * 16 + quad * 4] = o;
            }
        }
    }

    // ---- final PV(nch-1)
    {
        const int vp = (nch - 1) % 3;
        short8 pa0 = *(const short8*)&Pt[wv][lr][quad * 8];
        short8 pa1 = *(const short8*)&Pt[wv][16 + lr][quad * 8];
        #pragma unroll
        for (int nt = 0; nt < 8; ++nt) {
            short8 vf = *(const short8*)&Vb[vp][nt][lane * 8];
            O[0][nt] = MFMA16(vf, pa0, O[0][nt], 0, 0, 0);
            O[1][nt] = MFMA16(vf, pa1, O[1][nt], 0, 0, 0);
        }
    }

    // ---- sum over quads (same query lives at lanes lr, lr+16, lr+32, lr+48)
    #pragma unroll
    for (int m = 0; m < 2; ++m) {
        rs[m] += __shfl_xor(rs[m], 16);
        rs[m] += __shfl_xor(rs[m], 32);
    }

    #pragma unroll
    for (int m = 0; m < 2; ++m) {
        const float inv = 1.0f / rs[m];
        u16* dst = ah + (rowb + q0 + m * 16 + lr) * (size_t)ATT_LD + h * DIM_;
        #pragma unroll
        for (int nt = 0; nt < 8; ++nt) {
            ushort4 o;
            o.x = f2bf(O[m][nt][0] * inv); o.y = f2bf(O[m][nt][1] * inv);
            o.z = f2bf(O[m][nt][2] * inv); o.w = f2bf(O[m][nt][3] * inv);
            *(ushort4*)(dst + nt * 16 + quad * 4) = o;
        }
    }
}

// ---------- GEMM2 (bf16 MFMA, no split-K): out = att @ Wproj ---------------
// 512 thr = 8 waves = (mt 0..1) x (col-quarter cq 0..3); full K=2048/wave.
__global__ __launch_bounds__(512) void gemm2_mfma(
    const u16* __restrict__ ah, const u16* __restrict__ wpth,
    float* __restrict__ out)
{
    const int bm = blockIdx.x * 32;
    const int tid = threadIdx.x;
    const int wv = tid >> 6, lane = tid & 63;
    const int lr = lane & 15, quad = lane >> 4;
    const int mt = wv & 1, cq = wv >> 1;

    const u16* arow  = ah + (size_t)(bm + mt * 16 + lr) * ATT_LD + quad * 8;
    const u16* w0row = wpth + (size_t)(cq * 32 + lr) * ATT_LD + quad * 8;
    const u16* w1row = w0row + (size_t)16 * ATT_LD;

    f32x4 acc0 = {0.f, 0.f, 0.f, 0.f}, acc1 = {0.f, 0.f, 0.f, 0.f};
    #pragma unroll 4
    for (int k0 = 0; k0 < ATT_LD; k0 += 32) {
        short8 a  = *(const short8*)(arow + k0);
        short8 w0 = *(const short8*)(w0row + k0);
        short8 w1 = *(const short8*)(w1row + k0);
        acc0 = MFMA16(w0, a, acc0, 0, 0, 0);   // C^T: out cols in regs
        acc1 = MFMA16(w1, a, acc1, 0, 0, 0);
    }
    float* orow = out + (size_t)(bm + mt * 16 + lr) * DIM_ + cq * 32;
    *(float4*)(orow + quad * 4)      = *(float4*)&acc0;
    *(float4*)(orow + 16 + quad * 4) = *(float4*)&acc1;
}

// ---------- launch ----------------------------------------------------------
extern "C" void kernel_launch(void* const* d_in, const int* in_sizes, int n_in,
                              void* d_out, int out_size, void* d_ws, size_t ws_size,
                              hipStream_t stream)
{
    const float* x     = (const float*)d_in[0];
    const float* Wqkv  = (const float*)d_in[1];
    const float* Wproj = (const float*)d_in[2];
    float* out = (float*)d_out;

    u16* xh   = (u16*)d_ws;
    u16* wth  = xh   + (size_t)NX;
    u16* wpth = wth  + (size_t)NWQ;
    u16* qkvb = wpth + (size_t)NWP;                         // 8192*3072
    u16* vg   = qkvb + (size_t)8192 * QKV_LD;               // 4*4*128*2048
    u16* ahp  = vg   + (size_t)BATCH_ * KVH_ * DIM_ * SEQ_; // 8192*2048

    convert_inputs<<<(NX + NWQ + NWP) / 256, 256, 0, stream>>>(
        x, Wqkv, Wproj, xh, wth, wpth);

    gemm1_mfma<<<dim3(QKV_LD / 64, 8192 / 128), 256, 0, stream>>>(
        xh, wth, qkvb, vg);

    attn_mfma<<<dim3(SEQ_ / 32, KVH_, BATCH_), 256, 0, stream>>>(qkvb, vg, ahp);

    gemm2_mfma<<<8192 / 32, 512, 0, stream>>>(ahp, wpth, out);
}

// Round 8
// 209.263 us; speedup vs baseline: 1.0923x; 1.0923x over previous
//
#include <hip/hip_runtime.h>
#include <math.h>

#define DIM_    128
#define QH_     16
#define KVH_    4
#define WIN_    512
#define BATCH_  4
#define SEQ_    2048
#define QKV_LD  3072
#define ATT_LD  2048

#define NX   (BATCH_*SEQ_*DIM_)   // 1048576
#define NWQ  (DIM_*QKV_LD)        // 393216
#define NWP  (ATT_LD*DIM_)        // 262144

typedef __attribute__((ext_vector_type(8))) short short8;
typedef __attribute__((ext_vector_type(4))) float f32x4;
typedef unsigned short u16;
typedef unsigned int u32;

__device__ __forceinline__ u16 f2bf(float f) {
    u32 u = __float_as_uint(f);
    u += 0x7fff + ((u >> 16) & 1);
    return (u16)(u >> 16);
}
__device__ __forceinline__ float bf2f(u16 u) {
    return __uint_as_float(((u32)u) << 16);
}
#define MFMA16 __builtin_amdgcn_mfma_f32_16x16x32_bf16

#if __has_builtin(__builtin_amdgcn_exp2f)
#define EXP2F __builtin_amdgcn_exp2f
#else
#define EXP2F exp2f
#endif

__device__ __forceinline__ void gload_lds16(const u16* g, u16* l) {
    __builtin_amdgcn_global_load_lds(
        (const __attribute__((address_space(1))) unsigned int*)(const void*)g,
        (__attribute__((address_space(3))) unsigned int*)(void*)l, 16, 0, 0);
}

// ---------- convert: xh = bf16(x); wth = bf16(Wqkv^T)[3072][128];
//            wpth = bf16(Wproj^T)[128][2048]
__global__ __launch_bounds__(256) void convert_inputs(
    const float* __restrict__ x, const float* __restrict__ Wqkv,
    const float* __restrict__ Wproj,
    u16* __restrict__ xh, u16* __restrict__ wth, u16* __restrict__ wpth)
{
    const int t = blockIdx.x * 256 + threadIdx.x;
    if (t < NX) {
        xh[t] = f2bf(x[t]);
    } else if (t < NX + NWQ) {
        const int u2 = t - NX;
        const int k = u2 & 127, n = u2 >> 7;
        wth[u2] = f2bf(Wqkv[(size_t)k * QKV_LD + n]);
    } else {
        const int u2 = t - NX - NWQ;
        const int k = u2 & 2047, n = u2 >> 11;
        wpth[u2] = f2bf(Wproj[(size_t)k * DIM_ + n]);
    }
}

// ---------- GEMM1 (bf16 MFMA, LDS-tiled): qkv = x @ Wqkv (unchanged) -------
__global__ __launch_bounds__(256) void gemm1_mfma(
    const u16* __restrict__ xh, const u16* __restrict__ wth,
    u16* __restrict__ qkvb, u16* __restrict__ vg)
{
    __shared__ u16 Ab[32][512];
    __shared__ u16 Bb[16][512];
    const int bn = blockIdx.x * 64;
    const int bm = blockIdx.y * 128;
    const int tid = threadIdx.x;
    const int wv = tid >> 6, lane = tid & 63;
    const int lr = lane & 15, quad = lane >> 4;
    const int lo = lane & 15, hi = lane >> 4;

    #pragma unroll
    for (int i = 0; i < 12; ++i) {
        const int idx = wv * 12 + i;
        if (idx < 32) {
            const int mt = idx >> 2, s = idx & 3;
            gload_lds16(xh + (size_t)(bm + mt * 16 + lo) * DIM_ + s * 32 + hi * 8,
                        &Ab[idx][0]);
        } else {
            const int j = idx - 32, nt = j >> 2, s = j & 3;
            gload_lds16(wth + (size_t)(bn + nt * 16 + lo) * DIM_ + s * 32 + hi * 8,
                        &Bb[j][0]);
        }
    }
    __syncthreads();

    const int wr = wv >> 1, wc = wv & 1;
    f32x4 acc[4][2] = {};
    if (bn < 2560) {                       // transposed: ushort4 stores
        #pragma unroll
        for (int s = 0; s < 4; ++s) {
            short8 af[4], bf[2];
            #pragma unroll
            for (int mt = 0; mt < 4; ++mt)
                af[mt] = *(const short8*)&Ab[(wr * 4 + mt) * 4 + s][lane * 8];
            #pragma unroll
            for (int nt = 0; nt < 2; ++nt)
                bf[nt] = *(const short8*)&Bb[(wc * 2 + nt) * 4 + s][lane * 8];
            #pragma unroll
            for (int mt = 0; mt < 4; ++mt)
                #pragma unroll
                for (int nt = 0; nt < 2; ++nt)
                    acc[mt][nt] = MFMA16(bf[nt], af[mt], acc[mt][nt], 0, 0, 0);
        }
        #pragma unroll
        for (int mt = 0; mt < 4; ++mt)
            #pragma unroll
            for (int nt = 0; nt < 2; ++nt) {
                ushort4 o;
                o.x = f2bf(acc[mt][nt][0]); o.y = f2bf(acc[mt][nt][1]);
                o.z = f2bf(acc[mt][nt][2]); o.w = f2bf(acc[mt][nt][3]);
                *(ushort4*)(qkvb
                    + (size_t)(bm + wr * 64 + mt * 16 + lr) * QKV_LD
                    + bn + wc * 32 + nt * 16 + quad * 4) = o;
            }
    } else {                               // V region: normal, seq in regs
        #pragma unroll
        for (int s = 0; s < 4; ++s) {
            short8 af[4], bf[2];
            #pragma unroll
            for (int mt = 0; mt < 4; ++mt)
                af[mt] = *(const short8*)&Ab[(wr * 4 + mt) * 4 + s][lane * 8];
            #pragma unroll
            for (int nt = 0; nt < 2; ++nt)
                bf[nt] = *(const short8*)&Bb[(wc * 2 + nt) * 4 + s][lane * 8];
            #pragma unroll
            for (int mt = 0; mt < 4; ++mt)
                #pragma unroll
                for (int nt = 0; nt < 2; ++nt)
                    acc[mt][nt] = MFMA16(af[mt], bf[nt], acc[mt][nt], 0, 0, 0);
        }
        #pragma unroll
        for (int mt = 0; mt < 4; ++mt)
            #pragma unroll
            for (int nt = 0; nt < 2; ++nt) {
                const int ncol = bn + wc * 32 + nt * 16 + lr - 2560;
                const int kvh = ncol >> 7, d = ncol & 127;
                const int m0 = bm + wr * 64 + mt * 16 + quad * 4;
                ushort4 o;
                o.x = f2bf(acc[mt][nt][0]); o.y = f2bf(acc[mt][nt][1]);
                o.z = f2bf(acc[mt][nt][2]); o.w = f2bf(acc[mt][nt][3]);
                *(ushort4*)(vg + ((size_t)((m0 >> 11) * KVH_ + kvh) * DIM_ + d)
                            * SEQ_ + (m0 & 2047)) = o;
            }
    }
}

// ---------- Attention: async-pipelined chunks, raw barrier + manual vmcnt --
// Block = (b, kvh, 32-q tile), 256 thr, wave = head. K/V in a 4-slot LDS
// ring; depth-2 prefetch. Raw s_barrier (NO compiler vmcnt(0) drain) +
// s_waitcnt vmcnt(8): chunk ch's 4 loads drained, ch+1/ch+2 (8 loads) stay
// in flight across the barrier. Each wave issues exactly 4 loads per iter
// (dummy re-stage past the end keeps the count uniform); WAR-safe: laggards
// at ch-1 read slot (ch+3)&3 != write slot (ch+2)&3.
__global__ __launch_bounds__(256) void attn_mfma(
    const u16* __restrict__ qkvb, const u16* __restrict__ vg,
    u16* __restrict__ ah)
{
    const int qt = blockIdx.x, kvh = blockIdx.y, b = blockIdx.z;
    const int q0 = qt << 5;
    const int tid = threadIdx.x;
    const int wv = tid >> 6, lane = tid & 63;
    const int lr = lane & 15, quad = lane >> 4;
    const int h = kvh * 4 + wv;

    __shared__ u16 Kb[4][8][512];    // 32KB  4-slot ring, sub p = nt*4+s
    __shared__ u16 Vb[4][8][512];    // 32KB
    __shared__ u16 Pt[4][32][36];    // 9KB   per-wave P^T [query][key]

    const float scale2 = 0.08838834764831845f * 1.4426950408889634f;
    const float slope2 = exp2f(-0.5f * (float)(h + 1)) * 1.4426950408889634f;
    const int jbase = max(0, q0 - WIN_);
    const int nch = (q0 + 32 - jbase) >> 5;
    const size_t rowb = (size_t)b * SEQ_;
    const u16* kg  = qkvb + rowb * QKV_LD + (QH_ + kvh) * DIM_;
    const u16* vgb = vg + (size_t)(b * KVH_ + kvh) * DIM_ * SEQ_;
    const int lo = lane & 15, hi = lane >> 4;

    // Q B-frags (query = lane role)
    short8 qf[2][4];
    #pragma unroll
    for (int m = 0; m < 2; ++m) {
        const u16* qp = qkvb + (rowb + q0 + m * 16 + lr) * QKV_LD
                        + h * DIM_ + quad * 8;
        #pragma unroll
        for (int s = 0; s < 4; ++s) qf[m][s] = *(const short8*)(qp + 32 * s);
    }

    // per-m linear coefficients: exponent = c*scale2 + alpha - slope2*j
    float alpha[2];
    #pragma unroll
    for (int m = 0; m < 2; ++m) {
        const int q = q0 + m * 16 + lr;
        const int rm = (q < WIN_) ? q : WIN_;
        alpha[m] = slope2 * (float)(q - rm);
    }

    f32x4 O[2][8] = {};              // O^T: regs = d, lane col = query
    float rs[2] = {0.f, 0.f};

    // stage(chunk -> slot): exactly 4 loads per wave
    #define STAGE(CH, SLOT) do {                                              \
        const int _jk = jbase + ((CH) << 5);                                  \
        _Pragma("unroll")                                                     \
        for (int _t = 0; _t < 2; ++_t) {                                      \
            const int _p = wv + _t * 4;                                       \
            gload_lds16(kg + (size_t)(_jk + (_p >> 2) * 16 + lo) * QKV_LD     \
                        + (_p & 3) * 32 + hi * 8, &Kb[(SLOT)][_p][0]);        \
            gload_lds16(vgb + (size_t)(_p * 16 + lo) * SEQ_ + _jk + hi * 8,   \
                        &Vb[(SLOT)][_p][0]);                                  \
        }                                                                     \
    } while (0)

    STAGE(0, 0);
    { const int c1 = (1 < nch) ? 1 : (nch - 1); STAGE(c1, 1); }

    for (int ch = 0; ch < nch; ++ch) {
        const int jk = jbase + (ch << 5);
        const int slot = ch & 3;
        // depth-2 prefetch (dummy re-stage keeps vmcnt count uniform)
        { const int cn = (ch + 2 < nch) ? (ch + 2) : (nch - 1);
          STAGE(cn, (ch + 2) & 3); }
        // drain chunk ch's 4 loads; keep 8 newest (ch+1, ch+2) in flight
        __asm__ volatile("s_waitcnt vmcnt(8)" ::: "memory");
        __asm__ volatile("s_barrier" ::: "memory");

        // ---- QK(ch) transposed: C^T[key][query]
        #pragma unroll
        for (int nt = 0; nt < 2; ++nt) {
            f32x4 c0 = {0.f, 0.f, 0.f, 0.f}, c1 = {0.f, 0.f, 0.f, 0.f};
            #pragma unroll
            for (int s = 0; s < 4; ++s) {
                short8 kf = *(const short8*)&Kb[slot][nt * 4 + s][lane * 8];
                c0 = MFMA16(kf, qf[0][s], c0, 0, 0, 0);
                c1 = MFMA16(kf, qf[1][s], c1, 0, 0, 0);
            }
            const int jknt = jk + nt * 16;
            #pragma unroll
            for (int m = 0; m < 2; ++m) {
                const f32x4 c = m ? c1 : c0;
                const int qm0 = q0 + m * 16;
                const float b0 = fmaf(-slope2, (float)(jknt + quad * 4), alpha[m]);
                float e0, e1, e2, e3;
                if (qm0 >= jknt + 15 && qm0 + 15 <= jknt + WIN_) {   // full
                    e0 = EXP2F(fmaf(c[0], scale2, b0));
                    e1 = EXP2F(fmaf(c[1], scale2, b0 - slope2));
                    e2 = EXP2F(fmaf(c[2], scale2, b0 - 2.f * slope2));
                    e3 = EXP2F(fmaf(c[3], scale2, b0 - 3.f * slope2));
                } else {                                              // edge
                    const int q = qm0 + lr, j0q = jknt + quad * 4;
                    float ee[4];
                    #pragma unroll
                    for (int r = 0; r < 4; ++r) {
                        const int rel = q - (j0q + r);
                        const float t = fmaf(c[r], scale2, b0 - (float)r * slope2);
                        ee[r] = ((unsigned)rel <= (unsigned)WIN_) ? EXP2F(t) : 0.f;
                    }
                    e0 = ee[0]; e1 = ee[1]; e2 = ee[2]; e3 = ee[3];
                }
                rs[m] += (e0 + e1) + (e2 + e3);
                ushort4 o;
                o.x = f2bf(e0); o.y = f2bf(e1); o.z = f2bf(e2); o.w = f2bf(e3);
                *(ushort4*)&Pt[wv][m * 16 + lr][nt * 16 + quad * 4] = o;
            }
        }
        // intra-wave: P writes before P reads (in-order DS) + data wait
        __asm__ volatile("s_waitcnt lgkmcnt(0)" ::: "memory");

        // ---- PV(ch)
        short8 pa0 = *(const short8*)&Pt[wv][lr][quad * 8];
        short8 pa1 = *(const short8*)&Pt[wv][16 + lr][quad * 8];
        #pragma unroll
        for (int nt = 0; nt < 8; ++nt) {
            short8 vf = *(const short8*)&Vb[slot][nt][lane * 8];
            O[0][nt] = MFMA16(vf, pa0, O[0][nt], 0, 0, 0);
            O[1][nt] = MFMA16(vf, pa1, O[1][nt], 0, 0, 0);
        }
    }
    #undef STAGE

    // drain outstanding LDS-DMA before endpgm (LDS is deallocated at exit)
    __asm__ volatile("s_waitcnt vmcnt(0)" ::: "memory");

    // sum over quads (same query at lanes lr, lr+16, lr+32, lr+48)
    #pragma unroll
    for (int m = 0; m < 2; ++m) {
        rs[m] += __shfl_xor(rs[m], 16);
        rs[m] += __shfl_xor(rs[m], 32);
    }

    #pragma unroll
    for (int m = 0; m < 2; ++m) {
        const float inv = 1.0f / rs[m];
        u16* dst = ah + (rowb + q0 + m * 16 + lr) * (size_t)ATT_LD + h * DIM_;
        #pragma unroll
        for (int nt = 0; nt < 8; ++nt) {
            ushort4 o;
            o.x = f2bf(O[m][nt][0] * inv); o.y = f2bf(O[m][nt][1] * inv);
            o.z = f2bf(O[m][nt][2] * inv); o.w = f2bf(O[m][nt][3] * inv);
            *(ushort4*)(dst + nt * 16 + quad * 4) = o;
        }
    }
}

// ---------- GEMM2 (bf16 MFMA, no split-K): out = att @ Wproj (unchanged) ---
__global__ __launch_bounds__(512) void gemm2_mfma(
    const u16* __restrict__ ah, const u16* __restrict__ wpth,
    float* __restrict__ out)
{
    const int bm = blockIdx.x * 32;
    const int tid = threadIdx.x;
    const int wv = tid >> 6, lane = tid & 63;
    const int lr = lane & 15, quad = lane >> 4;
    const int mt = wv & 1, cq = wv >> 1;

    const u16* arow  = ah + (size_t)(bm + mt * 16 + lr) * ATT_LD + quad * 8;
    const u16* w0row = wpth + (size_t)(cq * 32 + lr) * ATT_LD + quad * 8;
    const u16* w1row = w0row + (size_t)16 * ATT_LD;

    f32x4 acc0 = {0.f, 0.f, 0.f, 0.f}, acc1 = {0.f, 0.f, 0.f, 0.f};
    #pragma unroll 4
    for (int k0 = 0; k0 < ATT_LD; k0 += 32) {
        short8 a  = *(const short8*)(arow + k0);
        short8 w0 = *(const short8*)(w0row + k0);
        short8 w1 = *(const short8*)(w1row + k0);
        acc0 = MFMA16(w0, a, acc0, 0, 0, 0);
        acc1 = MFMA16(w1, a, acc1, 0, 0, 0);
    }
    float* orow = out + (size_t)(bm + mt * 16 + lr) * DIM_ + cq * 32;
    *(float4*)(orow + quad * 4)      = *(float4*)&acc0;
    *(float4*)(orow + 16 + quad * 4) = *(float4*)&acc1;
}

// ---------- launch ----------------------------------------------------------
extern "C" void kernel_launch(void* const* d_in, const int* in_sizes, int n_in,
                              void* d_out, int out_size, void* d_ws, size_t ws_size,
                              hipStream_t stream)
{
    const float* x     = (const float*)d_in[0];
    const float* Wqkv  = (const float*)d_in[1];
    const float* Wproj = (const float*)d_in[2];
    float* out = (float*)d_out;

    u16* xh   = (u16*)d_ws;
    u16* wth  = xh   + (size_t)NX;
    u16* wpth = wth  + (size_t)NWQ;
    u16* qkvb = wpth + (size_t)NWP;                         // 8192*3072
    u16* vg   = qkvb + (size_t)8192 * QKV_LD;               // 4*4*128*2048
    u16* ahp  = vg   + (size_t)BATCH_ * KVH_ * DIM_ * SEQ_; // 8192*2048

    convert_inputs<<<(NX + NWQ + NWP) / 256, 256, 0, stream>>>(
        x, Wqkv, Wproj, xh, wth, wpth);

    gemm1_mfma<<<dim3(QKV_LD / 64, 8192 / 128), 256, 0, stream>>>(
        xh, wth, qkvb, vg);

    attn_mfma<<<dim3(SEQ_ / 32, KVH_, BATCH_), 256, 0, stream>>>(qkvb, vg, ahp);

    gemm2_mfma<<<8192 / 32, 512, 0, stream>>>(ahp, wpth, out);
}